// Round 13
// baseline (23.894 us; speedup 1.0000x reference)
//
#include <hip/hip_runtime.h>

// Path signature depth 4, path (N=64, L=512, C=8) fp32. Two kernels.
//
// k1: 512 blocks (n, g 0..7), 4 waves. Wave w: 16-step chunk signature in
//     registers (packed f2 math), then in-block 2-level TREE combine of the
//     4 chunk sigs -> partial (1/8 batch) -> ws. LDS trimmed to ~79KB
//     (sPA/sPB alias the dead zbuf) so 2 blocks/CU co-reside -> 2 waves/SIMD
//     during the chunk phase (R12 ran 1 wave/SIMD, zero TLP).
// k2: 256 blocks (n, c-quadrant w4): depth-3 tree combine of the 8 partials.
//     Evens staged A-layout, odds B-layout; every product is A x B form.
//     L123 redundantly computed per quadrant block; w4==0 stores it.
//
// R6: no atomic+fence cross-block handoff. R7: stores may skip the pre-store
// barrier only if the storing thread computed the element (true here).
// R11: serial product depth is the cost driver — keep trees shallow.
//
// LDS layouts for L123:
//   A-side (scalar access):  L1 [0,8), L2 [8,72), L3 at 72+(p*8+q)*9+r
//   B-side (float4 access):  L1/L2 flat,           L3 at 72+x*72+y*8+z
// L4 T-layout: float4 #i of lane l at f4-index i*64+l, covering
// (a=l>>3, b=l&7, c=i>>1, d=(i&1)*4..+3).

typedef float f2 __attribute__((ext_vector_type(2)));

#define NB 64
#define LP 512
#define SIG 4680
#define O2 8
#define O3 72
#define O4 584
#define SB 648

#define A3IDX(pq, r) (72 + (pq) * 9 + (r))
#define B3IDX(x, y, z) (72 + (x) * 72 + (y) * 8 + (z))

__device__ __forceinline__ f2 mkf2(float x, float y) { f2 r; r[0] = x; r[1] = y; return r; }

// ---------------------------------------------------------------------------
// k1: 512 blocks x 256 thr. 16-step chunks + in-block tree combine.
// ---------------------------------------------------------------------------
__global__ __launch_bounds__(256) void k1_sig(const float* __restrict__ path,
                                              float* __restrict__ ws)
{
    // uZP: zbuf (64*8=512 floats) aliased with sPA|sPB (2*648) — zbuf is dead
    // before level 1 writes sPA/sPB (publish barrier separates them).
    __shared__ __align__(16) float uZP[2 * SB];
    __shared__ __align__(16) float sA0[SB], sB1[SB], sA2[SB], sB3[SB];
    __shared__ __align__(16) float4 sT[4][1024];
    float* const zbuf = uZP;
    float* const sPA  = uZP;
    float* const sPB  = uZP + SB;

    const int tid = threadIdx.x;
    const int n = blockIdx.x >> 3;
    const int g = blockIdx.x & 7;

    if (tid < 128) {   // stage 64 increments (zero-padded past t=510)
        const int r = tid >> 1, hh = tid & 1;
        const int t = g * 64 + r;
        const float4* p4 = (const float4*)path + (size_t)n * (LP * 2);
        float4 z4 = make_float4(0.f, 0.f, 0.f, 0.f);
        if (t < LP - 1) {
            float4 x0 = p4[t * 2 + hh];
            float4 x1 = p4[t * 2 + 2 + hh];
            z4 = make_float4(x1.x - x0.x, x1.y - x0.y, x1.z - x0.z, x1.w - x0.w);
        }
        ((float4*)zbuf)[tid] = z4;
    }
    __syncthreads();

    const int w = tid >> 6, l = tid & 63;
    const int a = l >> 3, b = l & 7;
    const int f0 = 2 * tid;

    // ---- 16-step chunk signature in registers ----
    float s1 = 0.f, s2 = 0.f;
    f2 s3p[4], s4p[32];
    #pragma unroll
    for (int i = 0; i < 4; ++i) s3p[i] = mkf2(0.f, 0.f);
    #pragma unroll
    for (int e = 0; e < 32; ++e) s4p[e] = mkf2(0.f, 0.f);

    const float* zw = zbuf + w * (16 * 8);
    #pragma unroll 4
    for (int s = 0; s < 16; ++s) {
        const float* zs = zw + s * 8;
        f2 zp[4];
        #pragma unroll
        for (int j = 0; j < 4; ++j) zp[j] = ((const f2*)zs)[j];
        const float za  = zs[a];
        const float zbv = zs[b];
        const float B4 = zbv * (za * (1.f/24.f) + s1 * (1.f/6.f)) + s2 * 0.5f;
        const float G3 = zbv * (za * (1.f/6.f)  + s1 * 0.5f)      + s2;
        f2 Acp[4];
        #pragma unroll
        for (int i = 0; i < 4; ++i) Acp[i] = B4 * zp[i] + s3p[i];
        #pragma unroll
        for (int c = 0; c < 8; ++c) {
            const float Ac = Acp[c >> 1][c & 1];
            #pragma unroll
            for (int j = 0; j < 4; ++j) s4p[c * 4 + j] += Ac * zp[j];
        }
        #pragma unroll
        for (int i = 0; i < 4; ++i) s3p[i] += G3 * zp[i];
        s2 += zbv * (za * 0.5f + s1);
        s1 += za;
    }

    // ---- publish: S0->sA0, S2->sA2 (A-layout); S1->sB1, S3->sB3 (B-layout);
    //      all L4 -> sT[w] (T-layout). zbuf becomes dead here. ----
    if ((w & 1) == 0) {
        float* SA = (w == 0) ? sA0 : sA2;
        if (b == 0) SA[a] = s1;
        SA[O2 + l] = s2;
        #pragma unroll
        for (int c = 0; c < 8; ++c) SA[A3IDX(l, c)] = s3p[c >> 1][c & 1];
    } else {
        float* SL = (w == 1) ? sB1 : sB3;
        if (b == 0) SL[a] = s1;
        SL[O2 + l] = s2;
        *(float4*)&SL[B3IDX(a, b, 0)] = make_float4(s3p[0][0], s3p[0][1], s3p[1][0], s3p[1][1]);
        *(float4*)&SL[B3IDX(a, b, 4)] = make_float4(s3p[2][0], s3p[2][1], s3p[3][0], s3p[3][1]);
    }
    #pragma unroll
    for (int i = 0; i < 16; ++i)
        sT[w][i * 64 + l] = make_float4(s4p[2*i][0], s4p[2*i][1], s4p[2*i+1][0], s4p[2*i+1][1]);
    __syncthreads();

    // ---- level 1: half 0 -> P01 = S0 x S1, half 1 -> P23 = S2 x S3 ----
    {
        const int h  = tid >> 7;
        const int ht = tid & 127;
        const int hi = ht >> 6;
        const int la = (ht >> 3) & 7, lb = ht & 7;
        const float* SA  = h ? sA2 : sA0;
        const float* SBb = h ? sB3 : sB1;
        float4* TA = sT[h ? 2 : 0];          // in-place: becomes P.L4
        const float4* TB = sT[h ? 3 : 1];
        const int dh = hi * 4;
        const float A1  = SA[la];
        const float A2v = SA[O2 + la * 8 + lb];
        f2 b1p[2];
        *(float4*)&b1p[0] = *(const float4*)(SBb + dh);
        #pragma unroll
        for (int k = 0; k < 8; ++k) {        // k = c index
            const int f = k * 128 + ht;
            const float A3c = SA[A3IDX(la * 8 + lb, k)];
            f2 b2p[2], b3p[2];
            *(float4*)&b2p[0] = *(const float4*)(SBb + O2 + k * 8 + dh);
            *(float4*)&b3p[0] = *(const float4*)(SBb + B3IDX(lb, k, dh));
            float4 av = TA[f], bv = TB[f];
            f2 r0 = mkf2(av.x, av.y) + mkf2(bv.x, bv.y)
                  + A3c * b1p[0] + A2v * b2p[0] + A1 * b3p[0];
            f2 r1 = mkf2(av.z, av.w) + mkf2(bv.z, bv.w)
                  + A3c * b1p[1] + A2v * b2p[1] + A1 * b3p[1];
            TA[f] = make_float4(r0[0], r0[1], r1[0], r1[1]);
        }
        // L123 of the half's product: P01 -> sPA (A-layout), P23 -> sPB (B-layout)
        float* OP = h ? sPB : sPA;
        const int f3 = ht * 4;
        const int pp = f3 >> 6, qq = (f3 >> 3) & 7, rr = f3 & 7;   // rr in {0,4}
        const float A1p  = SA[pp];
        const float A2pq = SA[O2 + pp * 8 + qq];
        f2 bb1[2], bb2[2], bb3[2];
        *(float4*)&bb1[0] = *(const float4*)(SBb + rr);
        *(float4*)&bb2[0] = *(const float4*)(SBb + O2 + qq * 8 + rr);
        *(float4*)&bb3[0] = *(const float4*)(SBb + B3IDX(pp, qq, rr));
        float o[4];
        #pragma unroll
        for (int j = 0; j < 4; ++j)
            o[j] = SA[A3IDX(pp * 8 + qq, rr + j)] + bb3[j >> 1][j & 1]
                 + A2pq * bb1[j >> 1][j & 1] + A1p * bb2[j >> 1][j & 1];
        if (h == 0) {
            #pragma unroll
            for (int j = 0; j < 4; ++j) OP[A3IDX(pp * 8 + qq, rr + j)] = o[j];
        } else {
            *(float4*)&OP[B3IDX(pp, qq, rr)] = make_float4(o[0], o[1], o[2], o[3]);
        }
        if (ht < 64) OP[O2 + ht] = SA[O2 + ht] + SBb[O2 + ht] + SA[ht >> 3] * SBb[ht & 7];
        if (ht < 8)  OP[ht] = SA[ht] + SBb[ht];
    }
    __syncthreads();

    // ---- level 2: P = P01 x P23; every element stored by its computer ----
    {
        const int c0 = 2 * w;
        f2 a4[8], b4[8];
        #pragma unroll
        for (int k = 0; k < 4; ++k) {
            float4 v = sT[0][(w * 4 + k) * 64 + l];
            a4[2*k] = mkf2(v.x, v.y); a4[2*k+1] = mkf2(v.z, v.w);
            float4 u = sT[2][(w * 4 + k) * 64 + l];
            b4[2*k] = mkf2(u.x, u.y); b4[2*k+1] = mkf2(u.z, u.w);
        }
        const float A1  = sPA[a];
        const float A2v = sPA[O2 + a * 8 + b];
        const float A3_0 = sPA[A3IDX(a * 8 + b, c0)];
        const float A3_1 = sPA[A3IDX(a * 8 + b, c0 + 1)];
        f2 b1p[4], b2p[8], b3p[8];
        *(float4*)&b1p[0] = *(const float4*)(sPB);
        *(float4*)&b1p[2] = *(const float4*)(sPB + 4);
        #pragma unroll
        for (int i = 0; i < 4; ++i) {
            *(float4*)&b2p[2*i] = *(const float4*)(sPB + O2 + c0 * 8 + 4 * i);
            *(float4*)&b3p[2*i] = *(const float4*)(sPB + B3IDX(b, c0, 0) + 4 * i);
        }
        #pragma unroll
        for (int cc = 0; cc < 2; ++cc) {
            const float A3c = cc ? A3_1 : A3_0;
            #pragma unroll
            for (int j = 0; j < 4; ++j)
                a4[cc*4+j] += b4[cc*4+j] + A3c * b1p[j]
                            + A2v * b2p[cc*4+j] + A1 * b3p[cc*4+j];
        }

        float* dst = ws + (size_t)blockIdx.x * SIG;
        float4* dT = (float4*)(dst + O4);
        #pragma unroll
        for (int k = 0; k < 4; ++k)
            dT[(w * 4 + k) * 64 + l] =
                make_float4(a4[2*k][0], a4[2*k][1], a4[2*k+1][0], a4[2*k+1][1]);
        const int pp = f0 >> 6, qq = (f0 >> 3) & 7, rr = f0 & 7;
        const float A1p  = sPA[pp];
        const float A2pq = sPA[O2 + pp * 8 + qq];
        dst[O3 + f0]     = sPA[A3IDX(pp*8+qq, rr)]     + sPB[B3IDX(pp, qq, rr)]
                         + A2pq * sPB[rr]     + A1p * sPB[O2 + qq * 8 + rr];
        dst[O3 + f0 + 1] = sPA[A3IDX(pp*8+qq, rr + 1)] + sPB[B3IDX(pp, qq, rr + 1)]
                         + A2pq * sPB[rr + 1] + A1p * sPB[O2 + qq * 8 + rr + 1];
        if (tid < 64) dst[O2 + tid] = sPA[O2 + tid] + sPB[O2 + tid] + sPA[tid >> 3] * sPB[tid & 7];
        if (tid < 8)  dst[tid] = sPA[tid] + sPB[tid];
    }
}

// ---------------------------------------------------------------------------
// k2 helpers: L4 slice product and L123 product (A-layout x B-layout).
// ---------------------------------------------------------------------------
__device__ __forceinline__ void l4slice(const float* PA, const float* PB,
                                        const f2 x[2], const f2 y[2], f2 r[2],
                                        int a, int b, int c, int dh)
{
    const float A1  = PA[a];
    const float A2v = PA[O2 + a * 8 + b];
    const float A3c = PA[A3IDX(a * 8 + b, c)];
    f2 b1p[2], b2p[2], b3p[2];
    *(float4*)&b1p[0] = *(const float4*)(PB + dh);
    *(float4*)&b2p[0] = *(const float4*)(PB + O2 + c * 8 + dh);
    *(float4*)&b3p[0] = *(const float4*)(PB + B3IDX(b, c, dh));
    #pragma unroll
    for (int j = 0; j < 2; ++j)
        r[j] = x[j] + y[j] + A3c * b1p[j] + A2v * b2p[j] + A1 * b3p[j];
}

template<bool ALAY>
__device__ __forceinline__ void l123prod(const float* PA, const float* PB,
                                         float* OUT, int tid)
{
    const int f0 = 2 * tid;
    const int pp = f0 >> 6, qq = (f0 >> 3) & 7, rr = f0 & 7;
    const float A1p  = PA[pp];
    const float A2pq = PA[O2 + pp * 8 + qq];
    #pragma unroll
    for (int j = 0; j < 2; ++j) {
        const float v = PA[A3IDX(pp * 8 + qq, rr + j)] + PB[B3IDX(pp, qq, rr + j)]
                      + A2pq * PB[rr + j] + A1p * PB[O2 + qq * 8 + rr + j];
        if (ALAY) OUT[A3IDX(pp * 8 + qq, rr + j)] = v;
        else      OUT[B3IDX(pp, qq, rr + j)] = v;
    }
    if (tid < 64) OUT[O2 + tid] = PA[O2 + tid] + PB[O2 + tid] + PA[tid >> 3] * PB[tid & 7];
    if (tid < 8)  OUT[tid] = PA[tid] + PB[tid];
}

// ---------------------------------------------------------------------------
// k2: 256 blocks x 256 thr = (batch n, c-quadrant w4). Depth-3 tree of 8.
// ---------------------------------------------------------------------------
__global__ __launch_bounds__(256) void k2_final(const float* __restrict__ ws,
                                                float* __restrict__ out)
{
    __shared__ __align__(16) float sAe[4][SB], sBo[4][SB];   // staged sigs
    __shared__ __align__(16) float sP[4][SB];                // level-1 L123

    const int tid = threadIdx.x;
    const int n  = blockIdx.x >> 2;
    const int w4 = blockIdx.x & 3;
    const int a = tid >> 5, b = (tid >> 2) & 7, q = tid & 3;
    const int cc = q >> 1, dh4 = q & 1;
    const int c  = 2 * w4 + cc;
    const int dh = dh4 * 4;
    const int f0 = 2 * tid;
    const float* base = ws + (size_t)n * 8 * SIG;

    // own L4 quadrant f4 of all 8 sigs FIRST (latency overlaps staging)
    const int ti = (w4 * 4 + cc * 2 + dh4) * 64 + (a * 8 + b);
    f2 r[8][2];
    #pragma unroll
    for (int m = 0; m < 8; ++m) {
        float4 u = ((const float4*)(base + (size_t)m * SIG + O4))[ti];
        r[m][0] = mkf2(u.x, u.y); r[m][1] = mkf2(u.z, u.w);
    }

    // stage: evens -> A-layout, odds -> B-layout
    #pragma unroll
    for (int i = 0; i < 4; ++i) {
        const float* se = base + (size_t)(2 * i) * SIG;
        const float* so = base + (size_t)(2 * i + 1) * SIG;
        if (tid < O3) sAe[i][tid] = se[tid];
        sAe[i][A3IDX(f0 >> 3, f0 & 7)]       = se[O3 + f0];
        sAe[i][A3IDX(f0 >> 3, (f0 & 7) + 1)] = se[O3 + f0 + 1];
        if (tid < 146) {
            int d4 = (tid < 18) ? tid : 18 + ((tid - 18) >> 4) * 18 + ((tid - 18) & 15);
            ((float4*)sBo[i])[d4] = ((const float4*)so)[tid];
        }
    }
    __syncthreads();

    // ---- level 1: 4 pair products ----
    f2 p01[2], p23[2], p45[2], p67[2];
    l4slice(sAe[0], sBo[0], r[0], r[1], p01, a, b, c, dh);
    l4slice(sAe[1], sBo[1], r[2], r[3], p23, a, b, c, dh);
    l4slice(sAe[2], sBo[2], r[4], r[5], p45, a, b, c, dh);
    l4slice(sAe[3], sBo[3], r[6], r[7], p67, a, b, c, dh);
    l123prod<true >(sAe[0], sBo[0], sP[0], tid);   // P01 A-layout
    l123prod<false>(sAe[1], sBo[1], sP[1], tid);   // P23 B-layout
    l123prod<true >(sAe[2], sBo[2], sP[2], tid);   // P45 A-layout
    l123prod<false>(sAe[3], sBo[3], sP[3], tid);   // P67 B-layout
    __syncthreads();

    // ---- level 2: 2 products (outputs reuse dead sAe[0]/sBo[0]) ----
    f2 pAB[2], pCD[2];
    l4slice(sP[0], sP[1], p01, p23, pAB, a, b, c, dh);
    l4slice(sP[2], sP[3], p45, p67, pCD, a, b, c, dh);
    l123prod<true >(sP[0], sP[1], sAe[0], tid);    // Q0123 A-layout
    l123prod<false>(sP[2], sP[3], sBo[0], tid);    // Q4567 B-layout
    __syncthreads();

    // ---- level 3: final; every element stored by its computer ----
    float* dst = out + (size_t)n * SIG;
    {
        f2 rf[2];
        l4slice(sAe[0], sBo[0], pAB, pCD, rf, a, b, c, dh);
        ((float4*)(dst + O4))[((a * 8 + b) * 8 + c) * 2 + dh4] =
            make_float4(rf[0][0], rf[0][1], rf[1][0], rf[1][1]);
    }
    if (w4 == 0) {   // L123 identical across quadrant blocks; store once
        const int pp = f0 >> 6, qq = (f0 >> 3) & 7, rr = f0 & 7;
        const float* PA = sAe[0];
        const float* PB = sBo[0];
        const float A1p  = PA[pp];
        const float A2pq = PA[O2 + pp * 8 + qq];
        dst[O3 + f0]     = PA[A3IDX(pp*8+qq, rr)]     + PB[B3IDX(pp, qq, rr)]
                         + A2pq * PB[rr]     + A1p * PB[O2 + qq * 8 + rr];
        dst[O3 + f0 + 1] = PA[A3IDX(pp*8+qq, rr + 1)] + PB[B3IDX(pp, qq, rr + 1)]
                         + A2pq * PB[rr + 1] + A1p * PB[O2 + qq * 8 + rr + 1];
        if (tid < 64) dst[O2 + tid] = PA[O2 + tid] + PB[O2 + tid] + PA[tid >> 3] * PB[tid & 7];
        if (tid < 8)  dst[tid] = PA[tid] + PB[tid];
    }
}

extern "C" void kernel_launch(void* const* d_in, const int* in_sizes, int n_in,
                              void* d_out, int out_size, void* d_ws, size_t ws_size,
                              hipStream_t stream) {
    const float* path = (const float*)d_in[0];
    float* out = (float*)d_out;
    float* ws  = (float*)d_ws;   // 512 * 4680 * 4 B = 9.58 MB used

    k1_sig<<<NB * 8, 256, 0, stream>>>(path, ws);
    k2_final<<<NB * 4, 256, 0, stream>>>(ws, out);
}